// Round 11
// baseline (4385.837 us; speedup 1.0000x reference)
//
#include <hip/hip_runtime.h>

#define N_USERS 200000
#define N_ITEMS 100000
#define NTOT    300000          // N_USERS + N_ITEMS
#define NNZ     4000000
#define DIM     64
#define TOT_F   (NTOT * DIM)            // 19,200,000 floats
#define TOT_F4  (TOT_F / 4)
#define USER_F4 ((N_USERS * DIM) / 4)

#define NCB     1172            // coarse buckets of 256 rows
#define CAP     3712            // fixed bucket capacity (mean 3413, +5sigma)
#define GPAD    16              // global cursor padding (own 64B line)
#define NPB     250             // k_pb2 blocks; 250*4000 int4 = 1M = NNZ/4

typedef unsigned short ushort_t;
typedef unsigned long long u64_t;

__device__ __forceinline__ ushort_t f2bf(float f) {
    unsigned u = __float_as_uint(f);
    unsigned r = (u + 0x7FFFu + ((u >> 16) & 1u)) >> 16;   // RNE
    return (ushort_t)r;
}
__device__ __forceinline__ float bf2f(ushort_t b) {
    return __uint_as_float(((unsigned)b) << 16);
}

// ====================== bf16 conversion of concat(ue,ie) ===================
__global__ __launch_bounds__(256) void k_cvt(const float* __restrict__ ue,
                                             const float* __restrict__ ie,
                                             ushort_t* __restrict__ b0) {
    int i = blockIdx.x * blockDim.x + threadIdx.x;     // 8-float chunk id
    if (i >= TOT_F / 8) return;
    const float4* src = (i < USER_F4 / 2)
        ? reinterpret_cast<const float4*>(ue) + 2 * i
        : reinterpret_cast<const float4*>(ie) + 2 * i - USER_F4;
    float4 a = src[0], b = src[1];
    ushort_t o[8] = { f2bf(a.x), f2bf(a.y), f2bf(a.z), f2bf(a.w),
                      f2bf(b.x), f2bf(b.y), f2bf(b.z), f2bf(b.w) };
    reinterpret_cast<uint4*>(b0)[i] = *reinterpret_cast<uint4*>(o);
}

// =================== build: exclusive-region bucket scatter ================
// bseg record: hi = rowlocal<<24 | col ; lo = val bits

__global__ __launch_bounds__(256) void k_pb2(const int* __restrict__ rows,
                                             const int* __restrict__ cols,
                                             const float* __restrict__ vals,
                                             int* __restrict__ gcur,
                                             u64_t* __restrict__ bseg) {
    __shared__ int bh[NCB];
    int b = blockIdx.x, t = threadIdx.x;
    for (int i = t; i < NCB; i += 256) bh[i] = 0;
    __syncthreads();
    const int i0 = b * 4000, i1 = i0 + 4000;           // int4 range
    const int4* r4 = reinterpret_cast<const int4*>(rows);
    const int4* c4 = reinterpret_cast<const int4*>(cols);
    const float4* v4 = reinterpret_cast<const float4*>(vals);
    for (int i = i0 + t; i < i1; i += 256) {
        int4 r = r4[i];
        atomicAdd(&bh[r.x >> 8], 1);
        atomicAdd(&bh[r.y >> 8], 1);
        atomicAdd(&bh[r.z >> 8], 1);
        atomicAdd(&bh[r.w >> 8], 1);
    }
    __syncthreads();
    for (int k = t; k < NCB; k += 256) {
        int c = bh[k];
        bh[k] = c ? atomicAdd(&gcur[k * GPAD], c) : 0;
    }
    __syncthreads();
    for (int i = i0 + t; i < i1; i += 256) {
        int4   r = r4[i];
        int4   c = c4[i];
        float4 v = v4[i];
#define PUT(RR, CC, VV)                                                    \
        {                                                                  \
            int k = (RR) >> 8;                                             \
            int p = atomicAdd(&bh[k], 1);                                  \
            unsigned hi = (((unsigned)(RR) & 255u) << 24) | (unsigned)(CC);\
            bseg[(size_t)k * CAP + p] =                                    \
                ((u64_t)hi << 32) | (unsigned)__float_as_int(VV);          \
        }
        PUT(r.x, c.x, v.x)
        PUT(r.y, c.y, v.y)
        PUT(r.z, c.z, v.z)
        PUT(r.w, c.w, v.w)
#undef PUT
    }
}

// ================= SpMM: one block per bucket, LDS accumulator =============
// 512 threads = 8 waves split the bucket's edges. Per edge: uniform 8B record,
// 64-lane ushort gather (one 128B line), v*x -> LDS atomicAdd acc[rowlocal][lane].

template<int LAYER>
__global__ __launch_bounds__(512) void k_spmm_b(const int* __restrict__ gcur,
                                                const u64_t* __restrict__ bseg,
                                                const ushort_t* __restrict__ src,
                                                const float* __restrict__ ue,
                                                const float* __restrict__ ie,
                                                ushort_t* __restrict__ dstb,
                                                float* __restrict__ out) {
    __shared__ float lacc[256 * DIM];            // 64 KB
    int b = blockIdx.x, t = threadIdx.x;
    int lane = t & 63;
    int w = t >> 6;                              // wave 0..7

    for (int i = t; i < 256 * DIM; i += 512) lacc[i] = 0.f;
    __syncthreads();

    int tot = gcur[b * GPAD];
    const u64_t* seg = bseg + (size_t)b * CAP;
    int s = (tot * w) >> 3;
    int e = (tot * (w + 1)) >> 3;
    const char* sp = reinterpret_cast<const char*>(src) + lane * 2;

    int i = s;
    for (; i + 8 <= e; i += 8) {
        u64_t q0 = seg[i + 0], q1 = seg[i + 1], q2 = seg[i + 2], q3 = seg[i + 3];
        u64_t q4 = seg[i + 4], q5 = seg[i + 5], q6 = seg[i + 6], q7 = seg[i + 7];
        unsigned h0 = (unsigned)(q0 >> 32), h1 = (unsigned)(q1 >> 32);
        unsigned h2 = (unsigned)(q2 >> 32), h3 = (unsigned)(q3 >> 32);
        unsigned h4 = (unsigned)(q4 >> 32), h5 = (unsigned)(q5 >> 32);
        unsigned h6 = (unsigned)(q6 >> 32), h7 = (unsigned)(q7 >> 32);
        float x0 = bf2f(*(const ushort_t*)(sp + ((size_t)(h0 & 0xFFFFFFu) << 7)));
        float x1 = bf2f(*(const ushort_t*)(sp + ((size_t)(h1 & 0xFFFFFFu) << 7)));
        float x2 = bf2f(*(const ushort_t*)(sp + ((size_t)(h2 & 0xFFFFFFu) << 7)));
        float x3 = bf2f(*(const ushort_t*)(sp + ((size_t)(h3 & 0xFFFFFFu) << 7)));
        float x4 = bf2f(*(const ushort_t*)(sp + ((size_t)(h4 & 0xFFFFFFu) << 7)));
        float x5 = bf2f(*(const ushort_t*)(sp + ((size_t)(h5 & 0xFFFFFFu) << 7)));
        float x6 = bf2f(*(const ushort_t*)(sp + ((size_t)(h6 & 0xFFFFFFu) << 7)));
        float x7 = bf2f(*(const ushort_t*)(sp + ((size_t)(h7 & 0xFFFFFFu) << 7)));
        atomicAdd(&lacc[(h0 >> 24) * DIM + lane], __int_as_float((int)(unsigned)q0) * x0);
        atomicAdd(&lacc[(h1 >> 24) * DIM + lane], __int_as_float((int)(unsigned)q1) * x1);
        atomicAdd(&lacc[(h2 >> 24) * DIM + lane], __int_as_float((int)(unsigned)q2) * x2);
        atomicAdd(&lacc[(h3 >> 24) * DIM + lane], __int_as_float((int)(unsigned)q3) * x3);
        atomicAdd(&lacc[(h4 >> 24) * DIM + lane], __int_as_float((int)(unsigned)q4) * x4);
        atomicAdd(&lacc[(h5 >> 24) * DIM + lane], __int_as_float((int)(unsigned)q5) * x5);
        atomicAdd(&lacc[(h6 >> 24) * DIM + lane], __int_as_float((int)(unsigned)q6) * x6);
        atomicAdd(&lacc[(h7 >> 24) * DIM + lane], __int_as_float((int)(unsigned)q7) * x7);
    }
    for (; i < e; ++i) {
        u64_t q = seg[i];
        unsigned h = (unsigned)(q >> 32);
        float x = bf2f(*(const ushort_t*)(sp + ((size_t)(h & 0xFFFFFFu) << 7)));
        atomicAdd(&lacc[(h >> 24) * DIM + lane], __int_as_float((int)(unsigned)q) * x);
    }
    __syncthreads();

    // epilogue: wave w handles rows w*32 .. w*32+31 of this bucket
    int rl0 = w * 32;
    for (int k = 0; k < 32; ++k) {
        int rg = b * 256 + rl0 + k;
        if (rg >= NTOT) break;
        float acc = lacc[(rl0 + k) * DIM + lane];
        size_t o = (size_t)rg * DIM + lane;
        if (LAYER == 1) {
            float base = (rg < N_USERS) ? ue[o] : ie[o - (size_t)N_USERS * DIM];
            out[o] = base + acc;
            dstb[o] = f2bf(acc);
        } else if (LAYER == 2) {
            out[o] += acc;
            dstb[o] = f2bf(acc);
        } else {
            out[o] = (out[o] + acc) * 0.25f;
        }
    }
}

// ===================== fallback (atomic path, small ws) ====================

template<bool FROM_INPUTS>
__global__ __launch_bounds__(256) void scatter_kernel(
        const float* __restrict__ vals, const int* __restrict__ rows,
        const int* __restrict__ cols, const float* __restrict__ src,
        const float* __restrict__ ue, const float* __restrict__ ie,
        float* __restrict__ dst) {
    const int e = blockIdx.x * (blockDim.x >> 4) + (threadIdx.x >> 4);
    const int lane = threadIdx.x & 15;
    if (e >= NNZ) return;
    const float v = vals[e];
    const int c = cols[e];
    const int r = rows[e];
    const float* s = FROM_INPUTS
        ? ((c < N_USERS) ? (ue + (size_t)c * DIM) : (ie + (size_t)(c - N_USERS) * DIM))
        : (src + (size_t)c * DIM);
    const float4 x = reinterpret_cast<const float4*>(s)[lane];
    float* d = dst + (size_t)r * DIM + (size_t)lane * 4;
    atomicAdd(d + 0, v * x.x); atomicAdd(d + 1, v * x.y);
    atomicAdd(d + 2, v * x.z); atomicAdd(d + 3, v * x.w);
}

__global__ __launch_bounds__(256) void acc1_kernel(
        const float* __restrict__ ue, const float* __restrict__ ie,
        const float* __restrict__ a, float* __restrict__ out) {
    int i = blockIdx.x * blockDim.x + threadIdx.x;
    if (i >= TOT_F4) return;
    float4 base = (i < USER_F4)
        ? reinterpret_cast<const float4*>(ue)[i]
        : reinterpret_cast<const float4*>(ie)[i - USER_F4];
    float4 av = reinterpret_cast<const float4*>(a)[i];
    reinterpret_cast<float4*>(out)[i] =
        make_float4(base.x + av.x, base.y + av.y, base.z + av.z, base.w + av.w);
}

__global__ __launch_bounds__(256) void add_zero_kernel(
        const float* __restrict__ b, float* __restrict__ out,
        float* __restrict__ z) {
    int i = blockIdx.x * blockDim.x + threadIdx.x;
    if (i >= TOT_F4) return;
    float4 bv = reinterpret_cast<const float4*>(b)[i];
    float4 ov = reinterpret_cast<float4*>(out)[i];
    reinterpret_cast<float4*>(out)[i] =
        make_float4(ov.x + bv.x, ov.y + bv.y, ov.z + bv.z, ov.w + bv.w);
    reinterpret_cast<float4*>(z)[i] = make_float4(0.f, 0.f, 0.f, 0.f);
}

__global__ __launch_bounds__(256) void final_kernel(
        const float* __restrict__ b, float* __restrict__ out) {
    int i = blockIdx.x * blockDim.x + threadIdx.x;
    if (i >= TOT_F4) return;
    float4 bv = reinterpret_cast<const float4*>(b)[i];
    float4 ov = reinterpret_cast<float4*>(out)[i];
    reinterpret_cast<float4*>(out)[i] =
        make_float4((ov.x + bv.x) * 0.25f, (ov.y + bv.y) * 0.25f,
                    (ov.z + bv.z) * 0.25f, (ov.w + bv.w) * 0.25f);
}

// ===========================================================================

extern "C" void kernel_launch(void* const* d_in, const int* in_sizes, int n_in,
                              void* d_out, int out_size, void* d_ws, size_t ws_size,
                              hipStream_t stream)
{
    const float* ue   = (const float*)d_in[0];
    const float* ie   = (const float*)d_in[1];
    const float* vals = (const float*)d_in[2];
    const int*   rows = (const int*)  d_in[3];
    const int*   cols = (const int*)  d_in[4];
    float* out = (float*)d_out;

    // bf16 tables: 300000*64*2 = 38,400,000 bytes each
    const size_t BBUF   = (size_t)TOT_F * 2;
    const size_t O_B1   = BBUF;
    const size_t O_B2   = 2 * BBUF;
    const size_t O_BSEG = 3 * BBUF;                        // own region now
    const size_t O_GC   = O_BSEG + (size_t)NCB * CAP * 8;
    const size_t NEED   = O_GC + (size_t)NCB * GPAD * 4 + 4096;   // ~150.4 MB

    if (ws_size >= NEED) {
        ushort_t*  b0   = (ushort_t*)d_ws;
        ushort_t*  b1   = (ushort_t*)((char*)d_ws + O_B1);
        ushort_t*  b2   = (ushort_t*)((char*)d_ws + O_B2);
        u64_t*     bseg = (u64_t*)   ((char*)d_ws + O_BSEG);
        int*       gcur = (int*)((char*)d_ws + O_GC);

        const int cg = (TOT_F / 8 + 255) / 256;      // 9375

        hipMemsetAsync(gcur, 0, (size_t)NCB * GPAD * 4, stream);
        k_cvt<<<cg, 256, 0, stream>>>(ue, ie, b0);
        k_pb2<<<NPB, 256, 0, stream>>>(rows, cols, vals, gcur, bseg);

        k_spmm_b<1><<<NCB, 512, 0, stream>>>(gcur, bseg, b0, ue, ie, b1, out);
        k_spmm_b<2><<<NCB, 512, 0, stream>>>(gcur, bseg, b1, ue, ie, b2, out);
        k_spmm_b<3><<<NCB, 512, 0, stream>>>(gcur, bseg, b2, ue, ie, nullptr, out);
    } else {
        const size_t BUF = (size_t)TOT_F * sizeof(float);
        float* ws0 = (float*)d_ws;
        float* ws1 = (float*)((char*)d_ws + BUF);
        const int eb = 256;
        const int eg2 = (TOT_F4 + eb - 1) / eb;
        const int sg2 = (NNZ + 15) / 16;
        hipMemsetAsync(ws0, 0, BUF, stream);
        hipMemsetAsync(ws1, 0, BUF, stream);
        scatter_kernel<true><<<sg2, 256, 0, stream>>>(vals, rows, cols,
                                                      nullptr, ue, ie, ws0);
        acc1_kernel<<<eg2, eb, 0, stream>>>(ue, ie, ws0, out);
        scatter_kernel<false><<<sg2, 256, 0, stream>>>(vals, rows, cols,
                                                       ws0, nullptr, nullptr, ws1);
        add_zero_kernel<<<eg2, eb, 0, stream>>>(ws1, out, ws0);
        scatter_kernel<false><<<sg2, 256, 0, stream>>>(vals, rows, cols,
                                                       ws1, nullptr, nullptr, ws0);
        final_kernel<<<eg2, eb, 0, stream>>>(ws0, out);
    }
}

// Round 12
// 597.928 us; speedup vs baseline: 7.3351x; 7.3351x over previous
//
#include <hip/hip_runtime.h>

#define N_USERS 200000
#define N_ITEMS 100000
#define NTOT    300000          // N_USERS + N_ITEMS
#define NNZ     4000000
#define DIM     64
#define TOT_F   (NTOT * DIM)            // 19,200,000 floats
#define TOT_F4  (TOT_F / 4)
#define USER_F4 ((N_USERS * DIM) / 4)

#define NCB     1172            // coarse buckets of 256 rows
#define CAP     3712            // fixed bucket capacity (mean 3413, +5sigma)
#define CAP2    (CAP + 32)      // ecv stride: +32 zero-pad slots per bucket
#define GPAD    16              // global cursor padding (own 64B line)
#define NPB     250             // pb2 blocks; 250*4000 int4 = 1M = NNZ/4
#define CG      ((TOT_F / 8 + 255) / 256)   // 9375 cvt blocks

typedef unsigned short ushort_t;
typedef unsigned long long u64_t;

__device__ __forceinline__ ushort_t f2bf(float f) {
    unsigned u = __float_as_uint(f);
    unsigned r = (u + 0x7FFFu + ((u >> 16) & 1u)) >> 16;   // RNE
    return (ushort_t)r;
}

// ============ fused build: blocks [0,NPB) bucket-scatter, rest bf16 cvt ====
// bseg record: hi = rowlocal<<24 | col ; lo = val bits

__global__ __launch_bounds__(256) void k_build(const float* __restrict__ ue,
                                               const float* __restrict__ ie,
                                               const int* __restrict__ rows,
                                               const int* __restrict__ cols,
                                               const float* __restrict__ vals,
                                               int* __restrict__ gcur,
                                               u64_t* __restrict__ bseg,
                                               ushort_t* __restrict__ b0) {
    __shared__ int bh[NCB];
    if (blockIdx.x >= NPB) {
        // ---- cvt part: concat(ue,ie) -> bf16 table b0
        int i = (blockIdx.x - NPB) * 256 + threadIdx.x;    // 8-float chunk id
        if (i >= TOT_F / 8) return;
        const float4* src = (i < USER_F4 / 2)
            ? reinterpret_cast<const float4*>(ue) + 2 * i
            : reinterpret_cast<const float4*>(ie) + 2 * i - USER_F4;
        float4 a = src[0], b = src[1];
        ushort_t o[8] = { f2bf(a.x), f2bf(a.y), f2bf(a.z), f2bf(a.w),
                          f2bf(b.x), f2bf(b.y), f2bf(b.z), f2bf(b.w) };
        reinterpret_cast<uint4*>(b0)[i] = *reinterpret_cast<uint4*>(o);
        return;
    }
    // ---- pb2 part: exclusive-region bucket scatter
    int b = blockIdx.x, t = threadIdx.x;
    for (int i = t; i < NCB; i += 256) bh[i] = 0;
    __syncthreads();
    const int i0 = b * 4000, i1 = i0 + 4000;           // int4 range
    const int4* r4 = reinterpret_cast<const int4*>(rows);
    const int4* c4 = reinterpret_cast<const int4*>(cols);
    const float4* v4 = reinterpret_cast<const float4*>(vals);
    for (int i = i0 + t; i < i1; i += 256) {
        int4 r = r4[i];
        atomicAdd(&bh[r.x >> 8], 1);
        atomicAdd(&bh[r.y >> 8], 1);
        atomicAdd(&bh[r.z >> 8], 1);
        atomicAdd(&bh[r.w >> 8], 1);
    }
    __syncthreads();
    for (int k = t; k < NCB; k += 256) {
        int c = bh[k];
        bh[k] = c ? atomicAdd(&gcur[k * GPAD], c) : 0;
    }
    __syncthreads();
    for (int i = i0 + t; i < i1; i += 256) {
        int4   r = r4[i];
        int4   c = c4[i];
        float4 v = v4[i];
#define PUT(RR, CC, VV)                                                    \
        {                                                                  \
            int k = (RR) >> 8;                                             \
            int p = atomicAdd(&bh[k], 1);                                  \
            unsigned hi = (((unsigned)(RR) & 255u) << 24) | (unsigned)(CC);\
            bseg[(size_t)k * CAP + p] =                                    \
                ((u64_t)hi << 32) | (unsigned)__float_as_int(VV);          \
        }
        PUT(r.x, c.x, v.x)
        PUT(r.y, c.y, v.y)
        PUT(r.z, c.z, v.z)
        PUT(r.w, c.w, v.w)
#undef PUT
    }
}

// one block per bucket: row-sort segment, emit rstart2{start,end} + ecv + pads
// ecv record: hi = col*128 ; lo = val bits. ecv stride per bucket = CAP2.
__global__ __launch_bounds__(256) void k_rowsort(const int* __restrict__ gcur,
                                                 const u64_t* __restrict__ bseg,
                                                 long long* __restrict__ ecv,
                                                 int2* __restrict__ rstart2) {
    __shared__ int rh[256];
    __shared__ int rb[256];
    int b = blockIdx.x, t = threadIdx.x;
    int tot = gcur[b * GPAD];
    size_t segbase  = (size_t)b * CAP;
    size_t segbase2 = (size_t)b * CAP2;
    rh[t] = 0;
    __syncthreads();
    for (int e = t; e < tot; e += 256) {
        unsigned hi = (unsigned)(bseg[segbase + e] >> 32);
        atomicAdd(&rh[hi >> 24], 1);
    }
    __syncthreads();
    if (t == 0) {
        int run = 0;
        for (int i = 0; i < 256; ++i) { int c = rh[i]; rb[i] = run; run += c; }
    }
    __syncthreads();
    int row = b * 256 + t;
    if (row < NTOT)
        rstart2[row] = make_int2((int)segbase2 + rb[t],
                                 (int)segbase2 + rb[t] + rh[t]);
    rh[t] = rb[t];                       // reuse as cursors
    __syncthreads();
    for (int e = t; e < tot; e += 256) {
        u64_t q = bseg[segbase + e];
        unsigned hi = (unsigned)(q >> 32);
        int p = atomicAdd(&rh[hi >> 24], 1);
        ecv[segbase2 + p] = ((long long)((hi & 0x00FFFFFFu) << 7) << 32) |
                            (unsigned)q;
    }
    __syncthreads();
    if (t < 32) ecv[segbase2 + tot + t] = 0;   // overread pad (tot<=CAP=CAP2-32)
}

// ================== SpMM layer 1: bf16 gather, int8-quantizing epilogue ====
// One wave per row; 32-edge chunks; lanes 0-31 even slots, 32-63 odd;
// each lane covers 2 dims (ushort2 gather). Next chunk prefetched.

__global__ __launch_bounds__(256) void k_spmm1(const int2* __restrict__ rstart2,
                                               const long long* __restrict__ ecv,
                                               const ushort_t* __restrict__ src,
                                               const float* __restrict__ ue,
                                               const float* __restrict__ ie,
                                               signed char* __restrict__ dstq,
                                               float* __restrict__ dscale,
                                               float* __restrict__ out) {
    int wid  = blockIdx.x * 4 + (threadIdx.x >> 6);
    int lane = threadIdx.x & 63;
    if (wid >= NTOT) return;
    int2 se = rstart2[wid];
    int start = se.x, end = se.y;

    const int half = lane >> 5;
    const int d02  = (lane & 31) * 4;    // byte offset of dim pair (bf16 row)

    float acc0 = 0.f, acc1 = 0.f;
    long long q = ecv[start + (lane & 31)];
    for (int base = start; base < end; base += 32) {
        int rem = end - base;
        long long qn = q;
        if (rem > 32) qn = ecv[base + 32 + (lane & 31)];
        int qlo = (int)(unsigned)(q & 0xffffffffu);
        int qhi = (int)(unsigned)((unsigned long long)q >> 32);
        int remh = rem - half;
#pragma unroll
        for (int j = 0; j < 16; ++j) {
            int slot = 2 * j + half;
            float v  = __int_as_float(__shfl(qlo, slot));
            unsigned off = (unsigned)__shfl(qhi, slot);
            v = (2 * j < remh) ? v : 0.f;
            unsigned u = *reinterpret_cast<const unsigned*>(
                             reinterpret_cast<const char*>(src) + (off + d02));
            acc0 += v * __uint_as_float(u << 16);
            acc1 += v * __uint_as_float(u & 0xffff0000u);
        }
        q = qn;
    }
    acc0 += __shfl_xor(acc0, 32);
    acc1 += __shfl_xor(acc1, 32);

    // row max over the 32 dim-pairs -> int8 scale
    float m = fmaxf(fabsf(acc0), fabsf(acc1));
#pragma unroll
    for (int d = 1; d < 32; d <<= 1) m = fmaxf(m, __shfl_xor(m, d));
    float inv = (m > 1e-20f) ? 127.0f / m : 0.f;

    if (lane < 32) {
        size_t o = (size_t)wid * DIM + (size_t)lane * 2;
        const float* bsrc = (wid < N_USERS)
            ? ue + o : ie + (o - (size_t)N_USERS * DIM);
        float2 b2 = *reinterpret_cast<const float2*>(bsrc);
        __builtin_nontemporal_store(b2.x + acc0, out + o);
        __builtin_nontemporal_store(b2.y + acc1, out + o + 1);
        int q0 = (int)rintf(acc0 * inv);
        int q1 = (int)rintf(acc1 * inv);
        signed char pk[2] = { (signed char)q0, (signed char)q1 };
        *reinterpret_cast<short*>(dstq + (size_t)wid * DIM + (lane & 31) * 2) =
            *reinterpret_cast<const short*>(pk);
        if (lane == 0) dscale[wid] = m * (1.0f / 127.0f);
    }
}

// ============== SpMM layers 2/3: int8 gather (64B rows) + per-row scale ====

template<int LAYER>
__global__ __launch_bounds__(256) void k_spmm23(const int2* __restrict__ rstart2,
                                                const long long* __restrict__ ecv,
                                                const signed char* __restrict__ srcq,
                                                const float* __restrict__ sscale,
                                                signed char* __restrict__ dstq,
                                                float* __restrict__ dscale,
                                                float* __restrict__ out) {
    int wid  = blockIdx.x * 4 + (threadIdx.x >> 6);
    int lane = threadIdx.x & 63;
    if (wid >= NTOT) return;
    int2 se = rstart2[wid];
    int start = se.x, end = se.y;

    const int half = lane >> 5;
    const int d01  = (lane & 31) * 2;    // byte offset of dim pair (int8 row)

    float acc0 = 0.f, acc1 = 0.f;
    long long q = ecv[start + (lane & 31)];
    for (int base = start; base < end; base += 32) {
        int rem = end - base;
        long long qn = q;
        if (rem > 32) qn = ecv[base + 32 + (lane & 31)];
        int qlo = (int)(unsigned)(q & 0xffffffffu);
        int qhi = (int)(unsigned)((unsigned long long)q >> 32);
        int remh = rem - half;
#pragma unroll
        for (int j = 0; j < 16; ++j) {
            int slot = 2 * j + half;
            float v  = __int_as_float(__shfl(qlo, slot));
            unsigned off = (unsigned)__shfl(qhi, slot);   // col*128
            v = (2 * j < remh) ? v : 0.f;
            float sc = sscale[off >> 7];                  // broadcast, L2-hit
            char2 c2 = *reinterpret_cast<const char2*>(
                reinterpret_cast<const char*>(srcq) + ((off >> 1) + d01));
            float mm = v * sc;
            acc0 += mm * (float)c2.x;
            acc1 += mm * (float)c2.y;
        }
        q = qn;
    }
    acc0 += __shfl_xor(acc0, 32);
    acc1 += __shfl_xor(acc1, 32);

    float m = fmaxf(fabsf(acc0), fabsf(acc1));
#pragma unroll
    for (int d = 1; d < 32; d <<= 1) m = fmaxf(m, __shfl_xor(m, d));
    float inv = (m > 1e-20f) ? 127.0f / m : 0.f;

    if (lane < 32) {
        size_t o = (size_t)wid * DIM + (size_t)lane * 2;
        if (LAYER == 2) {
            float2 prev = *reinterpret_cast<const float2*>(out + o);
            __builtin_nontemporal_store(prev.x + acc0, out + o);
            __builtin_nontemporal_store(prev.y + acc1, out + o + 1);
            int q0 = (int)rintf(acc0 * inv);
            int q1 = (int)rintf(acc1 * inv);
            signed char pk[2] = { (signed char)q0, (signed char)q1 };
            *reinterpret_cast<short*>(dstq + (size_t)wid * DIM + (lane & 31) * 2) =
                *reinterpret_cast<const short*>(pk);
            if (lane == 0) dscale[wid] = m * (1.0f / 127.0f);
        } else {
            float2 prev = *reinterpret_cast<const float2*>(out + o);
            __builtin_nontemporal_store((prev.x + acc0) * 0.25f, out + o);
            __builtin_nontemporal_store((prev.y + acc1) * 0.25f, out + o + 1);
        }
    }
}

// ===================== fallback (atomic path, small ws) ====================

template<bool FROM_INPUTS>
__global__ __launch_bounds__(256) void scatter_kernel(
        const float* __restrict__ vals, const int* __restrict__ rows,
        const int* __restrict__ cols, const float* __restrict__ src,
        const float* __restrict__ ue, const float* __restrict__ ie,
        float* __restrict__ dst) {
    const int e = blockIdx.x * (blockDim.x >> 4) + (threadIdx.x >> 4);
    const int lane = threadIdx.x & 15;
    if (e >= NNZ) return;
    const float v = vals[e];
    const int c = cols[e];
    const int r = rows[e];
    const float* s = FROM_INPUTS
        ? ((c < N_USERS) ? (ue + (size_t)c * DIM) : (ie + (size_t)(c - N_USERS) * DIM))
        : (src + (size_t)c * DIM);
    const float4 x = reinterpret_cast<const float4*>(s)[lane];
    float* d = dst + (size_t)r * DIM + (size_t)lane * 4;
    atomicAdd(d + 0, v * x.x); atomicAdd(d + 1, v * x.y);
    atomicAdd(d + 2, v * x.z); atomicAdd(d + 3, v * x.w);
}

__global__ __launch_bounds__(256) void acc1_kernel(
        const float* __restrict__ ue, const float* __restrict__ ie,
        const float* __restrict__ a, float* __restrict__ out) {
    int i = blockIdx.x * blockDim.x + threadIdx.x;
    if (i >= TOT_F4) return;
    float4 base = (i < USER_F4)
        ? reinterpret_cast<const float4*>(ue)[i]
        : reinterpret_cast<const float4*>(ie)[i - USER_F4];
    float4 av = reinterpret_cast<const float4*>(a)[i];
    reinterpret_cast<float4*>(out)[i] =
        make_float4(base.x + av.x, base.y + av.y, base.z + av.z, base.w + av.w);
}

__global__ __launch_bounds__(256) void add_zero_kernel(
        const float* __restrict__ b, float* __restrict__ out,
        float* __restrict__ z) {
    int i = blockIdx.x * blockDim.x + threadIdx.x;
    if (i >= TOT_F4) return;
    float4 bv = reinterpret_cast<const float4*>(b)[i];
    float4 ov = reinterpret_cast<float4*>(out)[i];
    reinterpret_cast<float4*>(out)[i] =
        make_float4(ov.x + bv.x, ov.y + bv.y, ov.z + bv.z, ov.w + bv.w);
    reinterpret_cast<float4*>(z)[i] = make_float4(0.f, 0.f, 0.f, 0.f);
}

__global__ __launch_bounds__(256) void final_kernel(
        const float* __restrict__ b, float* __restrict__ out) {
    int i = blockIdx.x * blockDim.x + threadIdx.x;
    if (i >= TOT_F4) return;
    float4 bv = reinterpret_cast<const float4*>(b)[i];
    float4 ov = reinterpret_cast<float4*>(out)[i];
    reinterpret_cast<float4*>(out)[i] =
        make_float4((ov.x + bv.x) * 0.25f, (ov.y + bv.y) * 0.25f,
                    (ov.z + bv.z) * 0.25f, (ov.w + bv.w) * 0.25f);
}

// ===========================================================================

extern "C" void kernel_launch(void* const* d_in, const int* in_sizes, int n_in,
                              void* d_out, int out_size, void* d_ws, size_t ws_size,
                              hipStream_t stream)
{
    const float* ue   = (const float*)d_in[0];
    const float* ie   = (const float*)d_in[1];
    const float* vals = (const float*)d_in[2];
    const int*   rows = (const int*)  d_in[3];
    const int*   cols = (const int*)  d_in[4];
    float* out = (float*)d_out;

    const size_t O_B0   = 0;                                   // bf16 38.4MB
    const size_t O_B1I  = 38400000;                            // int8 19.2MB
    const size_t O_B2I  = O_B1I + 19200000;                    // int8 19.2MB
    const size_t O_SC1  = O_B2I + 19200000;                    // 1.2MB
    const size_t O_SC2  = O_SC1 + 1200000;                     // 1.2MB
    const size_t O_BSEG = O_SC2 + 1200000;                     // NCB*CAP*8
    const size_t O_ECV  = O_BSEG + (size_t)NCB * CAP * 8;      // NCB*CAP2*8
    const size_t O_GC   = O_ECV + (size_t)NCB * CAP2 * 8;
    const size_t O_RST  = O_GC + (size_t)NCB * GPAD * 4;
    const size_t NEED   = O_RST + (size_t)NTOT * 8 + 4096;     // ~151.6MB

    if (ws_size >= NEED) {
        ushort_t*    b0     = (ushort_t*)((char*)d_ws + O_B0);
        signed char* b1i    = (signed char*)((char*)d_ws + O_B1I);
        signed char* b2i    = (signed char*)((char*)d_ws + O_B2I);
        float*       sc1    = (float*)((char*)d_ws + O_SC1);
        float*       sc2    = (float*)((char*)d_ws + O_SC2);
        u64_t*       bseg   = (u64_t*)((char*)d_ws + O_BSEG);
        long long*   ecv    = (long long*)((char*)d_ws + O_ECV);
        int*         gcur   = (int*)((char*)d_ws + O_GC);
        int2*        rstart2= (int2*)((char*)d_ws + O_RST);

        const int sg = (NTOT + 3) / 4;               // 75000

        hipMemsetAsync(gcur, 0, (size_t)NCB * GPAD * 4, stream);
        k_build<<<NPB + CG, 256, 0, stream>>>(ue, ie, rows, cols, vals,
                                              gcur, bseg, b0);
        k_rowsort<<<NCB, 256, 0, stream>>>(gcur, bseg, ecv, rstart2);

        k_spmm1<<<sg, 256, 0, stream>>>(rstart2, ecv, b0, ue, ie,
                                        b1i, sc1, out);
        k_spmm23<2><<<sg, 256, 0, stream>>>(rstart2, ecv, b1i, sc1,
                                            b2i, sc2, out);
        k_spmm23<3><<<sg, 256, 0, stream>>>(rstart2, ecv, b2i, sc2,
                                            nullptr, nullptr, out);
    } else {
        const size_t BUF = (size_t)TOT_F * sizeof(float);
        float* ws0 = (float*)d_ws;
        float* ws1 = (float*)((char*)d_ws + BUF);
        const int eb = 256;
        const int eg2 = (TOT_F4 + eb - 1) / eb;
        const int sg2 = (NNZ + 15) / 16;
        hipMemsetAsync(ws0, 0, BUF, stream);
        hipMemsetAsync(ws1, 0, BUF, stream);
        scatter_kernel<true><<<sg2, 256, 0, stream>>>(vals, rows, cols,
                                                      nullptr, ue, ie, ws0);
        acc1_kernel<<<eg2, eb, 0, stream>>>(ue, ie, ws0, out);
        scatter_kernel<false><<<sg2, 256, 0, stream>>>(vals, rows, cols,
                                                       ws0, nullptr, nullptr, ws1);
        add_zero_kernel<<<eg2, eb, 0, stream>>>(ws1, out, ws0);
        scatter_kernel<false><<<sg2, 256, 0, stream>>>(vals, rows, cols,
                                                       ws1, nullptr, nullptr, ws0);
        final_kernel<<<eg2, eb, 0, stream>>>(ws0, out);
    }
}

// Round 13
// 548.170 us; speedup vs baseline: 8.0009x; 1.0908x over previous
//
#include <hip/hip_runtime.h>

#define N_USERS 200000
#define N_ITEMS 100000
#define NTOT    300000          // N_USERS + N_ITEMS
#define NNZ     4000000
#define DIM     64
#define TOT_F   (NTOT * DIM)            // 19,200,000 floats
#define TOT_F4  (TOT_F / 4)
#define USER_F4 ((N_USERS * DIM) / 4)

#define NCB     1172            // coarse buckets of 256 rows
#define CAP     3712            // fixed bucket capacity (mean 3413, +5sigma)
#define CAP2    (CAP + 32)      // ecv stride: +32 zero-pad slots per bucket
#define GPAD    16              // global cursor padding (own 64B line)
#define NPB     250             // pb2 blocks; 250*4000 int4 = 1M = NNZ/4
#define CG      ((TOT_F / 8 + 255) / 256)   // 9375 cvt blocks

typedef unsigned short ushort_t;
typedef unsigned long long u64_t;

__device__ __forceinline__ ushort_t f2bf(float f) {
    unsigned u = __float_as_uint(f);
    unsigned r = (u + 0x7FFFu + ((u >> 16) & 1u)) >> 16;   // RNE
    return (ushort_t)r;
}

// ============ fused build: blocks [0,NPB) bucket-scatter, rest bf16 cvt ====
// bseg record: hi = rowlocal<<24 | col ; lo = val bits

__global__ __launch_bounds__(256) void k_build(const float* __restrict__ ue,
                                               const float* __restrict__ ie,
                                               const int* __restrict__ rows,
                                               const int* __restrict__ cols,
                                               const float* __restrict__ vals,
                                               int* __restrict__ gcur,
                                               u64_t* __restrict__ bseg,
                                               ushort_t* __restrict__ b0) {
    __shared__ int bh[NCB];
    if (blockIdx.x >= NPB) {
        // ---- cvt part: concat(ue,ie) -> bf16 table b0
        int i = (blockIdx.x - NPB) * 256 + threadIdx.x;    // 8-float chunk id
        if (i >= TOT_F / 8) return;
        const float4* src = (i < USER_F4 / 2)
            ? reinterpret_cast<const float4*>(ue) + 2 * i
            : reinterpret_cast<const float4*>(ie) + 2 * i - USER_F4;
        float4 a = src[0], b = src[1];
        ushort_t o[8] = { f2bf(a.x), f2bf(a.y), f2bf(a.z), f2bf(a.w),
                          f2bf(b.x), f2bf(b.y), f2bf(b.z), f2bf(b.w) };
        reinterpret_cast<uint4*>(b0)[i] = *reinterpret_cast<uint4*>(o);
        return;
    }
    // ---- pb2 part: exclusive-region bucket scatter
    int b = blockIdx.x, t = threadIdx.x;
    for (int i = t; i < NCB; i += 256) bh[i] = 0;
    __syncthreads();
    const int i0 = b * 4000, i1 = i0 + 4000;           // int4 range
    const int4* r4 = reinterpret_cast<const int4*>(rows);
    const int4* c4 = reinterpret_cast<const int4*>(cols);
    const float4* v4 = reinterpret_cast<const float4*>(vals);
    for (int i = i0 + t; i < i1; i += 256) {
        int4 r = r4[i];
        atomicAdd(&bh[r.x >> 8], 1);
        atomicAdd(&bh[r.y >> 8], 1);
        atomicAdd(&bh[r.z >> 8], 1);
        atomicAdd(&bh[r.w >> 8], 1);
    }
    __syncthreads();
    for (int k = t; k < NCB; k += 256) {
        int c = bh[k];
        bh[k] = c ? atomicAdd(&gcur[k * GPAD], c) : 0;
    }
    __syncthreads();
    for (int i = i0 + t; i < i1; i += 256) {
        int4   r = r4[i];
        int4   c = c4[i];
        float4 v = v4[i];
#define PUT(RR, CC, VV)                                                    \
        {                                                                  \
            int k = (RR) >> 8;                                             \
            int p = atomicAdd(&bh[k], 1);                                  \
            unsigned hi = (((unsigned)(RR) & 255u) << 24) | (unsigned)(CC);\
            bseg[(size_t)k * CAP + p] =                                    \
                ((u64_t)hi << 32) | (unsigned)__float_as_int(VV);          \
        }
        PUT(r.x, c.x, v.x)
        PUT(r.y, c.y, v.y)
        PUT(r.z, c.z, v.z)
        PUT(r.w, c.w, v.w)
#undef PUT
    }
}

// one block per bucket: row-sort segment, emit rstart2{start,end} + ecv + pads
// ecv record: hi = col*128 (byte offset into bf16 table) ; lo = val bits.
__global__ __launch_bounds__(256) void k_rowsort(const int* __restrict__ gcur,
                                                 const u64_t* __restrict__ bseg,
                                                 long long* __restrict__ ecv,
                                                 int2* __restrict__ rstart2) {
    __shared__ int rh[256];
    __shared__ int rb[256];
    int b = blockIdx.x, t = threadIdx.x;
    int tot = gcur[b * GPAD];
    size_t segbase  = (size_t)b * CAP;
    size_t segbase2 = (size_t)b * CAP2;
    rh[t] = 0;
    __syncthreads();
    for (int e = t; e < tot; e += 256) {
        unsigned hi = (unsigned)(bseg[segbase + e] >> 32);
        atomicAdd(&rh[hi >> 24], 1);
    }
    __syncthreads();
    if (t == 0) {
        int run = 0;
        for (int i = 0; i < 256; ++i) { int c = rh[i]; rb[i] = run; run += c; }
    }
    __syncthreads();
    int row = b * 256 + t;
    if (row < NTOT)
        rstart2[row] = make_int2((int)segbase2 + rb[t],
                                 (int)segbase2 + rb[t] + rh[t]);
    rh[t] = rb[t];                       // reuse as cursors
    __syncthreads();
    for (int e = t; e < tot; e += 256) {
        u64_t q = bseg[segbase + e];
        unsigned hi = (unsigned)(q >> 32);
        int p = atomicAdd(&rh[hi >> 24], 1);
        ecv[segbase2 + p] = ((long long)((hi & 0x00FFFFFFu) << 7) << 32) |
                            (unsigned)q;
    }
    __syncthreads();
    if (t < 32) ecv[segbase2 + tot + t] = 0;   // overread pad
}

// ===================== SpMM (bf16 gather, 32-edge chunks) ==================
// One wave per row; lanes 0-31 even slots, 32-63 odd; each lane covers 2 dims
// via one ushort2 gather. Next 32-edge chunk prefetched.
// LAYER 1: out = base + acc ; dstb = bf16(acc)
// LAYER 2: out += acc       ; dstb = bf16(acc)
// LAYER 3: out = (out+acc)*0.25

template<int LAYER>
__global__ __launch_bounds__(256) void k_spmm(const int2* __restrict__ rstart2,
                                              const long long* __restrict__ ecv,
                                              const ushort_t* __restrict__ src,
                                              const float* __restrict__ ue,
                                              const float* __restrict__ ie,
                                              ushort_t* __restrict__ dstb,
                                              float* __restrict__ out) {
    int wid  = blockIdx.x * 4 + (threadIdx.x >> 6);
    int lane = threadIdx.x & 63;
    if (wid >= NTOT) return;
    int2 se = rstart2[wid];
    int start = se.x, end = se.y;

    const int half = lane >> 5;
    const int d02  = (lane & 31) * 4;    // byte offset of dim pair (bf16 row)

    float acc0 = 0.f, acc1 = 0.f;
    long long q = ecv[start + (lane & 31)];
    for (int base = start; base < end; base += 32) {
        int rem = end - base;
        long long qn = q;
        if (rem > 32) qn = ecv[base + 32 + (lane & 31)];
        int qlo = (int)(unsigned)(q & 0xffffffffu);
        int qhi = (int)(unsigned)((unsigned long long)q >> 32);
        int remh = rem - half;
#pragma unroll
        for (int j = 0; j < 16; ++j) {
            int slot = 2 * j + half;
            float v  = __int_as_float(__shfl(qlo, slot));
            unsigned off = (unsigned)__shfl(qhi, slot);
            v = (2 * j < remh) ? v : 0.f;
            unsigned u = *reinterpret_cast<const unsigned*>(
                             reinterpret_cast<const char*>(src) + (off + d02));
            acc0 += v * __uint_as_float(u << 16);
            acc1 += v * __uint_as_float(u & 0xffff0000u);
        }
        q = qn;
    }
    acc0 += __shfl_xor(acc0, 32);
    acc1 += __shfl_xor(acc1, 32);

    if (lane < 32) {
        size_t o = (size_t)wid * DIM + (size_t)lane * 2;
        unsigned pk = ((unsigned)f2bf(acc1) << 16) | (unsigned)f2bf(acc0);
        if (LAYER == 1) {
            const float* bsrc = (wid < N_USERS)
                ? ue + o : ie + (o - (size_t)N_USERS * DIM);
            float2 b2 = *reinterpret_cast<const float2*>(bsrc);
            __builtin_nontemporal_store(b2.x + acc0, out + o);
            __builtin_nontemporal_store(b2.y + acc1, out + o + 1);
            *reinterpret_cast<unsigned*>(dstb + o) = pk;
        } else if (LAYER == 2) {
            float2 prev = *reinterpret_cast<const float2*>(out + o);
            __builtin_nontemporal_store(prev.x + acc0, out + o);
            __builtin_nontemporal_store(prev.y + acc1, out + o + 1);
            *reinterpret_cast<unsigned*>(dstb + o) = pk;
        } else {
            float2 prev = *reinterpret_cast<const float2*>(out + o);
            __builtin_nontemporal_store((prev.x + acc0) * 0.25f, out + o);
            __builtin_nontemporal_store((prev.y + acc1) * 0.25f, out + o + 1);
        }
    }
}

// ===================== fallback (atomic path, small ws) ====================

template<bool FROM_INPUTS>
__global__ __launch_bounds__(256) void scatter_kernel(
        const float* __restrict__ vals, const int* __restrict__ rows,
        const int* __restrict__ cols, const float* __restrict__ src,
        const float* __restrict__ ue, const float* __restrict__ ie,
        float* __restrict__ dst) {
    const int e = blockIdx.x * (blockDim.x >> 4) + (threadIdx.x >> 4);
    const int lane = threadIdx.x & 15;
    if (e >= NNZ) return;
    const float v = vals[e];
    const int c = cols[e];
    const int r = rows[e];
    const float* s = FROM_INPUTS
        ? ((c < N_USERS) ? (ue + (size_t)c * DIM) : (ie + (size_t)(c - N_USERS) * DIM))
        : (src + (size_t)c * DIM);
    const float4 x = reinterpret_cast<const float4*>(s)[lane];
    float* d = dst + (size_t)r * DIM + (size_t)lane * 4;
    atomicAdd(d + 0, v * x.x); atomicAdd(d + 1, v * x.y);
    atomicAdd(d + 2, v * x.z); atomicAdd(d + 3, v * x.w);
}

__global__ __launch_bounds__(256) void acc1_kernel(
        const float* __restrict__ ue, const float* __restrict__ ie,
        const float* __restrict__ a, float* __restrict__ out) {
    int i = blockIdx.x * blockDim.x + threadIdx.x;
    if (i >= TOT_F4) return;
    float4 base = (i < USER_F4)
        ? reinterpret_cast<const float4*>(ue)[i]
        : reinterpret_cast<const float4*>(ie)[i - USER_F4];
    float4 av = reinterpret_cast<const float4*>(a)[i];
    reinterpret_cast<float4*>(out)[i] =
        make_float4(base.x + av.x, base.y + av.y, base.z + av.z, base.w + av.w);
}

__global__ __launch_bounds__(256) void add_zero_kernel(
        const float* __restrict__ b, float* __restrict__ out,
        float* __restrict__ z) {
    int i = blockIdx.x * blockDim.x + threadIdx.x;
    if (i >= TOT_F4) return;
    float4 bv = reinterpret_cast<const float4*>(b)[i];
    float4 ov = reinterpret_cast<float4*>(out)[i];
    reinterpret_cast<float4*>(out)[i] =
        make_float4(ov.x + bv.x, ov.y + bv.y, ov.z + bv.z, ov.w + bv.w);
    reinterpret_cast<float4*>(z)[i] = make_float4(0.f, 0.f, 0.f, 0.f);
}

__global__ __launch_bounds__(256) void final_kernel(
        const float* __restrict__ b, float* __restrict__ out) {
    int i = blockIdx.x * blockDim.x + threadIdx.x;
    if (i >= TOT_F4) return;
    float4 bv = reinterpret_cast<const float4*>(b)[i];
    float4 ov = reinterpret_cast<float4*>(out)[i];
    reinterpret_cast<float4*>(out)[i] =
        make_float4((ov.x + bv.x) * 0.25f, (ov.y + bv.y) * 0.25f,
                    (ov.z + bv.z) * 0.25f, (ov.w + bv.w) * 0.25f);
}

// ===========================================================================

extern "C" void kernel_launch(void* const* d_in, const int* in_sizes, int n_in,
                              void* d_out, int out_size, void* d_ws, size_t ws_size,
                              hipStream_t stream)
{
    const float* ue   = (const float*)d_in[0];
    const float* ie   = (const float*)d_in[1];
    const float* vals = (const float*)d_in[2];
    const int*   rows = (const int*)  d_in[3];
    const int*   cols = (const int*)  d_in[4];
    float* out = (float*)d_out;

    // bf16 tables: 300000*64*2 = 38,400,000 bytes each
    const size_t BBUF   = (size_t)TOT_F * 2;
    const size_t O_B1   = BBUF;
    const size_t O_B2   = 2 * BBUF;
    const size_t O_BSEG = O_B1;                 // bseg (34.8MB) aliases b1 (dead
                                                // until spmm1's epilogue; bseg is
                                                // consumed by rowsort before)
    const size_t O_ECV  = 3 * BBUF;             // NCB*CAP2*8 = 35.1MB
    const size_t O_GC   = O_ECV + (size_t)NCB * CAP2 * 8;
    const size_t O_RST  = O_GC + (size_t)NCB * GPAD * 4;
    const size_t NEED   = O_RST + (size_t)NTOT * 8 + 4096;   // ~155 MB

    if (ws_size >= NEED) {
        ushort_t*  b0     = (ushort_t*)d_ws;
        ushort_t*  b1     = (ushort_t*)((char*)d_ws + O_B1);
        ushort_t*  b2     = (ushort_t*)((char*)d_ws + O_B2);
        u64_t*     bseg   = (u64_t*)   ((char*)d_ws + O_BSEG);
        long long* ecv    = (long long*)((char*)d_ws + O_ECV);
        int*       gcur   = (int*)((char*)d_ws + O_GC);
        int2*      rstart2= (int2*)((char*)d_ws + O_RST);

        const int sg = (NTOT + 3) / 4;               // 75000

        hipMemsetAsync(gcur, 0, (size_t)NCB * GPAD * 4, stream);
        k_build<<<NPB + CG, 256, 0, stream>>>(ue, ie, rows, cols, vals,
                                              gcur, bseg, b0);
        k_rowsort<<<NCB, 256, 0, stream>>>(gcur, bseg, ecv, rstart2);

        k_spmm<1><<<sg, 256, 0, stream>>>(rstart2, ecv, b0, ue, ie, b1, out);
        k_spmm<2><<<sg, 256, 0, stream>>>(rstart2, ecv, b1, ue, ie, b2, out);
        k_spmm<3><<<sg, 256, 0, stream>>>(rstart2, ecv, b2, ue, ie, nullptr, out);
    } else {
        const size_t BUF = (size_t)TOT_F * sizeof(float);
        float* ws0 = (float*)d_ws;
        float* ws1 = (float*)((char*)d_ws + BUF);
        const int eb = 256;
        const int eg2 = (TOT_F4 + eb - 1) / eb;
        const int sg2 = (NNZ + 15) / 16;
        hipMemsetAsync(ws0, 0, BUF, stream);
        hipMemsetAsync(ws1, 0, BUF, stream);
        scatter_kernel<true><<<sg2, 256, 0, stream>>>(vals, rows, cols,
                                                      nullptr, ue, ie, ws0);
        acc1_kernel<<<eg2, eb, 0, stream>>>(ue, ie, ws0, out);
        scatter_kernel<false><<<sg2, 256, 0, stream>>>(vals, rows, cols,
                                                       ws0, nullptr, nullptr, ws1);
        add_zero_kernel<<<eg2, eb, 0, stream>>>(ws1, out, ws0);
        scatter_kernel<false><<<sg2, 256, 0, stream>>>(vals, rows, cols,
                                                       ws1, nullptr, nullptr, ws0);
        final_kernel<<<eg2, eb, 0, stream>>>(ws0, out);
    }
}

// Round 14
// 509.561 us; speedup vs baseline: 8.6071x; 1.0758x over previous
//
#include <hip/hip_runtime.h>

#define N_USERS 200000
#define N_ITEMS 100000
#define NTOT    300000          // N_USERS + N_ITEMS
#define NNZ     4000000
#define DIM     64
#define TOT_F   (NTOT * DIM)            // 19,200,000 floats
#define TOT_F4  (TOT_F / 4)
#define USER_F4 ((N_USERS * DIM) / 4)

#define NCB     1172            // coarse buckets of 256 rows
#define CAP     3712            // fixed bucket capacity (mean 3413, +5sigma)
#define CAP2    (CAP + 32)      // ecv stride: +32 zero-pad slots per bucket
#define GPAD    16              // global cursor padding (own 64B line)
#define NPB     250             // pb2 blocks; 250*4000 int4 = 1M = NNZ/4
#define CG      ((TOT_F / 8 + 255) / 256)   // 9375 cvt blocks

typedef unsigned short ushort_t;
typedef unsigned long long u64_t;

__device__ __forceinline__ ushort_t f2bf(float f) {
    unsigned u = __float_as_uint(f);
    unsigned r = (u + 0x7FFFu + ((u >> 16) & 1u)) >> 16;   // RNE
    return (ushort_t)r;
}

// ============ fused build: blocks [0,NPB) bucket-scatter, rest bf16 cvt ====
// bseg record: hi = rowlocal<<24 | col ; lo = val bits

__global__ __launch_bounds__(256) void k_build(const float* __restrict__ ue,
                                               const float* __restrict__ ie,
                                               const int* __restrict__ rows,
                                               const int* __restrict__ cols,
                                               const float* __restrict__ vals,
                                               int* __restrict__ gcur,
                                               u64_t* __restrict__ bseg,
                                               ushort_t* __restrict__ b0) {
    __shared__ int bh[NCB];
    if (blockIdx.x >= NPB) {
        // ---- cvt part: concat(ue,ie) -> bf16 table b0
        int i = (blockIdx.x - NPB) * 256 + threadIdx.x;    // 8-float chunk id
        if (i >= TOT_F / 8) return;
        const float4* src = (i < USER_F4 / 2)
            ? reinterpret_cast<const float4*>(ue) + 2 * i
            : reinterpret_cast<const float4*>(ie) + 2 * i - USER_F4;
        float4 a = src[0], b = src[1];
        ushort_t o[8] = { f2bf(a.x), f2bf(a.y), f2bf(a.z), f2bf(a.w),
                          f2bf(b.x), f2bf(b.y), f2bf(b.z), f2bf(b.w) };
        reinterpret_cast<uint4*>(b0)[i] = *reinterpret_cast<uint4*>(o);
        return;
    }
    // ---- pb2 part: exclusive-region bucket scatter
    int b = blockIdx.x, t = threadIdx.x;
    for (int i = t; i < NCB; i += 256) bh[i] = 0;
    __syncthreads();
    const int i0 = b * 4000, i1 = i0 + 4000;           // int4 range
    const int4* r4 = reinterpret_cast<const int4*>(rows);
    const int4* c4 = reinterpret_cast<const int4*>(cols);
    const float4* v4 = reinterpret_cast<const float4*>(vals);
    for (int i = i0 + t; i < i1; i += 256) {
        int4 r = r4[i];
        atomicAdd(&bh[r.x >> 8], 1);
        atomicAdd(&bh[r.y >> 8], 1);
        atomicAdd(&bh[r.z >> 8], 1);
        atomicAdd(&bh[r.w >> 8], 1);
    }
    __syncthreads();
    for (int k = t; k < NCB; k += 256) {
        int c = bh[k];
        bh[k] = c ? atomicAdd(&gcur[k * GPAD], c) : 0;
    }
    __syncthreads();
    for (int i = i0 + t; i < i1; i += 256) {
        int4   r = r4[i];
        int4   c = c4[i];
        float4 v = v4[i];
#define PUT(RR, CC, VV)                                                    \
        {                                                                  \
            int k = (RR) >> 8;                                             \
            int p = atomicAdd(&bh[k], 1);                                  \
            unsigned hi = (((unsigned)(RR) & 255u) << 24) | (unsigned)(CC);\
            bseg[(size_t)k * CAP + p] =                                    \
                ((u64_t)hi << 32) | (unsigned)__float_as_int(VV);          \
        }
        PUT(r.x, c.x, v.x)
        PUT(r.y, c.y, v.y)
        PUT(r.z, c.z, v.z)
        PUT(r.w, c.w, v.w)
#undef PUT
    }
}

// one block per bucket: row-sort segment, emit rstart2{start,end} + ecv + pads
// ecv record: hi = col*128 (byte offset into bf16 table) ; lo = val bits.
__global__ __launch_bounds__(256) void k_rowsort(const int* __restrict__ gcur,
                                                 const u64_t* __restrict__ bseg,
                                                 long long* __restrict__ ecv,
                                                 int2* __restrict__ rstart2) {
    __shared__ int rh[256];
    __shared__ int rb[256];
    int b = blockIdx.x, t = threadIdx.x;
    int tot = gcur[b * GPAD];
    size_t segbase  = (size_t)b * CAP;
    size_t segbase2 = (size_t)b * CAP2;
    rh[t] = 0;
    __syncthreads();
    for (int e = t; e < tot; e += 256) {
        unsigned hi = (unsigned)(bseg[segbase + e] >> 32);
        atomicAdd(&rh[hi >> 24], 1);
    }
    __syncthreads();
    if (t == 0) {
        int run = 0;
        for (int i = 0; i < 256; ++i) { int c = rh[i]; rb[i] = run; run += c; }
    }
    __syncthreads();
    int row = b * 256 + t;
    if (row < NTOT)
        rstart2[row] = make_int2((int)segbase2 + rb[t],
                                 (int)segbase2 + rb[t] + rh[t]);
    rh[t] = rb[t];                       // reuse as cursors
    __syncthreads();
    for (int e = t; e < tot; e += 256) {
        u64_t q = bseg[segbase + e];
        unsigned hi = (unsigned)(q >> 32);
        int p = atomicAdd(&rh[hi >> 24], 1);
        ecv[segbase2 + p] = ((long long)((hi & 0x00FFFFFFu) << 7) << 32) |
                            (unsigned)q;
    }
    __syncthreads();
    if (t < 32) ecv[segbase2 + tot + t] = 0;   // overread pad
}

// ===================== SpMM (bf16 gather, 16-edge chunks) ==================
// One wave per row; lanes 0-31 even slots, 32-63 odd; each lane covers 2 dims
// via one ushort2 gather. Inner loop 3-phase batched: 8x shfl, 8x independent
// gathers (deep VMEM queue), 8x masked FMA-pairs. Next chunk prefetched.

template<int LAYER>
__global__ __launch_bounds__(256) void k_spmm(const int2* __restrict__ rstart2,
                                              const long long* __restrict__ ecv,
                                              const ushort_t* __restrict__ src,
                                              const float* __restrict__ ue,
                                              const float* __restrict__ ie,
                                              ushort_t* __restrict__ dstb,
                                              float* __restrict__ out) {
    int wid  = blockIdx.x * 4 + (threadIdx.x >> 6);
    int lane = threadIdx.x & 63;
    if (wid >= NTOT) return;
    int2 se = rstart2[wid];
    int start = se.x, end = se.y;

    const int half = lane >> 5;
    const int d02  = (lane & 31) * 4;    // byte offset of dim pair (bf16 row)

    float acc0 = 0.f, acc1 = 0.f;
    long long q = ecv[start + (lane & 15)];
    for (int base = start; base < end; base += 16) {
        int rem = end - base;
        long long qn = q;
        if (rem > 16) qn = ecv[base + 16 + (lane & 15)];
        int qlo = (int)(unsigned)(q & 0xffffffffu);
        int qhi = (int)(unsigned)((unsigned long long)q >> 32);
        int remh = rem - half;

        float    v[8];
        unsigned off[8];
        unsigned u[8];
#pragma unroll
        for (int j = 0; j < 8; ++j) {
            int slot = 2 * j + half;
            v[j]   = __int_as_float(__shfl(qlo, slot));
            off[j] = (unsigned)__shfl(qhi, slot);
        }
#pragma unroll
        for (int j = 0; j < 8; ++j)
            u[j] = *reinterpret_cast<const unsigned*>(
                       reinterpret_cast<const char*>(src) + (off[j] + d02));
#pragma unroll
        for (int j = 0; j < 8; ++j) {
            float vv = (2 * j < remh) ? v[j] : 0.f;
            acc0 += vv * __uint_as_float(u[j] << 16);
            acc1 += vv * __uint_as_float(u[j] & 0xffff0000u);
        }
        q = qn;
    }
    acc0 += __shfl_xor(acc0, 32);
    acc1 += __shfl_xor(acc1, 32);

    if (lane < 32) {
        size_t o = (size_t)wid * DIM + (size_t)lane * 2;
        unsigned pk = ((unsigned)f2bf(acc1) << 16) | (unsigned)f2bf(acc0);
        if (LAYER == 1) {
            const float* bsrc = (wid < N_USERS)
                ? ue + o : ie + (o - (size_t)N_USERS * DIM);
            float2 b2 = *reinterpret_cast<const float2*>(bsrc);
            __builtin_nontemporal_store(b2.x + acc0, out + o);
            __builtin_nontemporal_store(b2.y + acc1, out + o + 1);
            *reinterpret_cast<unsigned*>(dstb + o) = pk;
        } else if (LAYER == 2) {
            float2 prev = *reinterpret_cast<const float2*>(out + o);
            __builtin_nontemporal_store(prev.x + acc0, out + o);
            __builtin_nontemporal_store(prev.y + acc1, out + o + 1);
            *reinterpret_cast<unsigned*>(dstb + o) = pk;
        } else {
            float2 prev = *reinterpret_cast<const float2*>(out + o);
            __builtin_nontemporal_store((prev.x + acc0) * 0.25f, out + o);
            __builtin_nontemporal_store((prev.y + acc1) * 0.25f, out + o + 1);
        }
    }
}

// ===================== fallback (atomic path, small ws) ====================

template<bool FROM_INPUTS>
__global__ __launch_bounds__(256) void scatter_kernel(
        const float* __restrict__ vals, const int* __restrict__ rows,
        const int* __restrict__ cols, const float* __restrict__ src,
        const float* __restrict__ ue, const float* __restrict__ ie,
        float* __restrict__ dst) {
    const int e = blockIdx.x * (blockDim.x >> 4) + (threadIdx.x >> 4);
    const int lane = threadIdx.x & 15;
    if (e >= NNZ) return;
    const float v = vals[e];
    const int c = cols[e];
    const int r = rows[e];
    const float* s = FROM_INPUTS
        ? ((c < N_USERS) ? (ue + (size_t)c * DIM) : (ie + (size_t)(c - N_USERS) * DIM))
        : (src + (size_t)c * DIM);
    const float4 x = reinterpret_cast<const float4*>(s)[lane];
    float* d = dst + (size_t)r * DIM + (size_t)lane * 4;
    atomicAdd(d + 0, v * x.x); atomicAdd(d + 1, v * x.y);
    atomicAdd(d + 2, v * x.z); atomicAdd(d + 3, v * x.w);
}

__global__ __launch_bounds__(256) void acc1_kernel(
        const float* __restrict__ ue, const float* __restrict__ ie,
        const float* __restrict__ a, float* __restrict__ out) {
    int i = blockIdx.x * blockDim.x + threadIdx.x;
    if (i >= TOT_F4) return;
    float4 base = (i < USER_F4)
        ? reinterpret_cast<const float4*>(ue)[i]
        : reinterpret_cast<const float4*>(ie)[i - USER_F4];
    float4 av = reinterpret_cast<const float4*>(a)[i];
    reinterpret_cast<float4*>(out)[i] =
        make_float4(base.x + av.x, base.y + av.y, base.z + av.z, base.w + av.w);
}

__global__ __launch_bounds__(256) void add_zero_kernel(
        const float* __restrict__ b, float* __restrict__ out,
        float* __restrict__ z) {
    int i = blockIdx.x * blockDim.x + threadIdx.x;
    if (i >= TOT_F4) return;
    float4 bv = reinterpret_cast<const float4*>(b)[i];
    float4 ov = reinterpret_cast<float4*>(out)[i];
    reinterpret_cast<float4*>(out)[i] =
        make_float4(ov.x + bv.x, ov.y + bv.y, ov.z + bv.z, ov.w + bv.w);
    reinterpret_cast<float4*>(z)[i] = make_float4(0.f, 0.f, 0.f, 0.f);
}

__global__ __launch_bounds__(256) void final_kernel(
        const float* __restrict__ b, float* __restrict__ out) {
    int i = blockIdx.x * blockDim.x + threadIdx.x;
    if (i >= TOT_F4) return;
    float4 bv = reinterpret_cast<const float4*>(b)[i];
    float4 ov = reinterpret_cast<float4*>(out)[i];
    reinterpret_cast<float4*>(out)[i] =
        make_float4((ov.x + bv.x) * 0.25f, (ov.y + bv.y) * 0.25f,
                    (ov.z + bv.z) * 0.25f, (ov.w + bv.w) * 0.25f);
}

// ===========================================================================

extern "C" void kernel_launch(void* const* d_in, const int* in_sizes, int n_in,
                              void* d_out, int out_size, void* d_ws, size_t ws_size,
                              hipStream_t stream)
{
    const float* ue   = (const float*)d_in[0];
    const float* ie   = (const float*)d_in[1];
    const float* vals = (const float*)d_in[2];
    const int*   rows = (const int*)  d_in[3];
    const int*   cols = (const int*)  d_in[4];
    float* out = (float*)d_out;

    // bf16 tables: 300000*64*2 = 38,400,000 bytes each
    const size_t BBUF   = (size_t)TOT_F * 2;
    const size_t O_B1   = BBUF;
    const size_t O_B2   = 2 * BBUF;
    const size_t O_BSEG = O_B1;                 // bseg (34.8MB) aliases b1 (dead
                                                // until spmm1's epilogue; bseg is
                                                // consumed by rowsort before)
    const size_t O_ECV  = 3 * BBUF;             // NCB*CAP2*8 = 35.1MB
    const size_t O_GC   = O_ECV + (size_t)NCB * CAP2 * 8;
    const size_t O_RST  = O_GC + (size_t)NCB * GPAD * 4;
    const size_t NEED   = O_RST + (size_t)NTOT * 8 + 4096;   // ~155 MB

    if (ws_size >= NEED) {
        ushort_t*  b0     = (ushort_t*)d_ws;
        ushort_t*  b1     = (ushort_t*)((char*)d_ws + O_B1);
        ushort_t*  b2     = (ushort_t*)((char*)d_ws + O_B2);
        u64_t*     bseg   = (u64_t*)   ((char*)d_ws + O_BSEG);
        long long* ecv    = (long long*)((char*)d_ws + O_ECV);
        int*       gcur   = (int*)((char*)d_ws + O_GC);
        int2*      rstart2= (int2*)((char*)d_ws + O_RST);

        const int sg = (NTOT + 3) / 4;               // 75000

        hipMemsetAsync(gcur, 0, (size_t)NCB * GPAD * 4, stream);
        k_build<<<NPB + CG, 256, 0, stream>>>(ue, ie, rows, cols, vals,
                                              gcur, bseg, b0);
        k_rowsort<<<NCB, 256, 0, stream>>>(gcur, bseg, ecv, rstart2);

        k_spmm<1><<<sg, 256, 0, stream>>>(rstart2, ecv, b0, ue, ie, b1, out);
        k_spmm<2><<<sg, 256, 0, stream>>>(rstart2, ecv, b1, ue, ie, b2, out);
        k_spmm<3><<<sg, 256, 0, stream>>>(rstart2, ecv, b2, ue, ie, nullptr, out);
    } else {
        const size_t BUF = (size_t)TOT_F * sizeof(float);
        float* ws0 = (float*)d_ws;
        float* ws1 = (float*)((char*)d_ws + BUF);
        const int eb = 256;
        const int eg2 = (TOT_F4 + eb - 1) / eb;
        const int sg2 = (NNZ + 15) / 16;
        hipMemsetAsync(ws0, 0, BUF, stream);
        hipMemsetAsync(ws1, 0, BUF, stream);
        scatter_kernel<true><<<sg2, 256, 0, stream>>>(vals, rows, cols,
                                                      nullptr, ue, ie, ws0);
        acc1_kernel<<<eg2, eb, 0, stream>>>(ue, ie, ws0, out);
        scatter_kernel<false><<<sg2, 256, 0, stream>>>(vals, rows, cols,
                                                       ws0, nullptr, nullptr, ws1);
        add_zero_kernel<<<eg2, eb, 0, stream>>>(ws1, out, ws0);
        scatter_kernel<false><<<sg2, 256, 0, stream>>>(vals, rows, cols,
                                                       ws1, nullptr, nullptr, ws0);
        final_kernel<<<eg2, eb, 0, stream>>>(ws0, out);
    }
}